// Round 18
// baseline (1079.616 us; speedup 1.0000x reference)
//
#include <hip/hip_runtime.h>

#define ROWS 32768      // B*T
#define D 512
#define NCODES 8192
#define KC 384          // OpenBLAS sgemm kc panel split (verified exact, rounds 4-17)
#define NTILES 64       // 8192 codes / 128
#define NSLOT 64

typedef _Float16 h8 __attribute__((ext_vector_type(8)));
typedef float f4v __attribute__((ext_vector_type(4)));

// ---------------- kernel 1: fused prep ----------------
// Wave-per-row: vector-convert row to f16 (cb scaled 2^12), then np-exact
// pairwise sumsq chains (strided re-reads are L1-hot), sabs, and zeroing of
// cnt/tileCnt (absorbs the old memsets; runs before k_select in stream order).
__global__ __launch_bounds__(256)
void k_prep(const float* __restrict__ zE, const float* __restrict__ cb,
            _Float16* __restrict__ zh, _Float16* __restrict__ ch,
            float* __restrict__ sq, float* __restrict__ e2,
            float* __restrict__ sabs, int* __restrict__ cnt,
            int* __restrict__ tileCnt) {
    const int wid  = blockIdx.x * 4 + (threadIdx.x >> 6);   // 0..40959
    const int lane = threadIdx.x & 63;
    const bool isrow = wid < ROWS;
    const float* p = isrow ? zE + (size_t)wid * D
                           : cb + (size_t)(wid - ROWS) * D;

    // f16 conversion (identical values to rounds 12-17's k_half)
    {
        float4 u = *(const float4*)(p + lane * 8);
        float4 v = *(const float4*)(p + lane * 8 + 4);
        if (isrow) {
            h8 o = {(_Float16)u.x, (_Float16)u.y, (_Float16)u.z, (_Float16)u.w,
                    (_Float16)v.x, (_Float16)v.y, (_Float16)v.z, (_Float16)v.w};
            *(h8*)(zh + (size_t)wid * D + lane * 8) = o;
        } else {
            h8 o = {(_Float16)(u.x * 4096.0f), (_Float16)(u.y * 4096.0f),
                    (_Float16)(u.z * 4096.0f), (_Float16)(u.w * 4096.0f),
                    (_Float16)(v.x * 4096.0f), (_Float16)(v.y * 4096.0f),
                    (_Float16)(v.z * 4096.0f), (_Float16)(v.w * 4096.0f)};
            *(h8*)(ch + (size_t)(wid - ROWS) * D + lane * 8) = o;
        }
    }

    // np-pairwise-exact sumsq (verified chain structure, rounds 15-17)
    float v;
    if (lane < 32) {
        const int b = lane >> 3, j = lane & 7;
        const float* q = p + b * 128 + j;
        float r = __fmul_rn(q[0], q[0]);
#pragma unroll
        for (int i = 1; i < 16; ++i) {
            float t = q[i * 8];
            r = __fadd_rn(r, __fmul_rn(t, t));
        }
        v = r;
    } else {
        const int m = lane - 32;
        float sa = 0.0f;
#pragma unroll
        for (int i = 0; i < 16; ++i) sa += fabsf(p[i * 32 + m]);
        v = sa;
    }
    v = __fadd_rn(v, __shfl_xor(v, 1));
    v = __fadd_rn(v, __shfl_xor(v, 2));
    v = __fadd_rn(v, __shfl_xor(v, 4));
    v = __fadd_rn(v, __shfl_xor(v, 8));
    v = __fadd_rn(v, __shfl_xor(v, 16));
    float sa = __shfl(v, 32);
    if (lane == 0) {
        if (isrow) { sq[wid] = v; sabs[wid] = sa; cnt[wid] = 0; }
        else       { e2[wid - ROWS] = v; }
    }
    if (lane == 1 && wid < NTILES) tileCnt[wid] = 0;
}

// approx distance (deterministic; identical in both MFMA kernels)
__device__ __forceinline__ float dapprox(float s, float accv, float ecv) {
    float m = __fmul_rn(accv, 0.000244140625f);       // exact /4096
    return __fadd_rn(__fsub_rn(s, __fmul_rn(2.0f, m)), ecv);
}

// ---------------- kernel 2: fp16 MFMA pass 1 -> per-tile minima ----------------
// 2-wave blocks (4 blocks/CU): lighter barriers, 4 independent pipelines per CU.
// LDS layout linear [frag][lane] (global_load_lds contract); MFMA accumulate
// order identical to rounds 12-17 -> d~ bit-identical.
__global__ __launch_bounds__(128, 2)
void k_mfma_min(const _Float16* __restrict__ zh, const _Float16* __restrict__ ch,
                const float* __restrict__ sq, const float* __restrict__ e2,
                float* __restrict__ tmin) {
    __shared__ h8 AB[2 * 1024];   // [buf][A: 2w x 4a x 64 | B: 8b x 64] = 32 KiB

    const int p    = blockIdx.x;                      // 0..16383
    const int ct   = (p & 7) * 8 + ((p >> 3) & 7);    // code tile 0..63 (XCD-local)
    const int rt   = p >> 6;                          // row tile 0..255
    const int wvu  = __builtin_amdgcn_readfirstlane(threadIdx.x >> 6);  // 0..1
    const int lane = threadIdx.x & 63;
    const int l15  = lane & 15;
    const int lk   = lane >> 4;
    const int rw   = rt * 128 + wvu * 64;
    const int cw   = ct * 128;

    f4v acc[4][8];
#pragma unroll
    for (int a = 0; a < 4; ++a)
#pragma unroll
        for (int b = 0; b < 8; ++b) acc[a][b] = (f4v){0.f, 0.f, 0.f, 0.f};

#define STAGE(buf, k0c)                                                              \
    {                                                                                \
        _Pragma("unroll")                                                            \
        for (int a = 0; a < 4; ++a) {                                                \
            const _Float16* src = zh + (size_t)(rw + a * 16 + l15) * D + (k0c) + lk * 8; \
            __builtin_amdgcn_global_load_lds(                                        \
                (const __attribute__((address_space(1))) void*)(const void*)src,    \
                (__attribute__((address_space(3))) void*)(void*)&AB[(buf) * 1024 + wvu * 256 + a * 64], \
                16, 0, 0);                                                           \
        }                                                                            \
        _Pragma("unroll")                                                            \
        for (int j = 0; j < 4; ++j) {                                                \
            const int bb = wvu * 4 + j;                                              \
            const _Float16* src = ch + (size_t)(cw + bb * 16 + l15) * D + (k0c) + lk * 8; \
            __builtin_amdgcn_global_load_lds(                                        \
                (const __attribute__((address_space(1))) void*)(const void*)src,    \
                (__attribute__((address_space(3))) void*)(void*)&AB[(buf) * 1024 + 512 + bb * 64], \
                16, 0, 0);                                                           \
        }                                                                            \
    }

    STAGE(0, 0);
    int cur = 0;
#pragma unroll 1
    for (int ks = 0; ks < 16; ++ks) {                 // k0 = ks*32, ascending
        __syncthreads();                              // staged buf `cur` ready
        if (ks < 15) STAGE(cur ^ 1, (ks + 1) * 32);   // async prefetch next
        h8 bf[8];
#pragma unroll
        for (int b = 0; b < 8; ++b) bf[b] = AB[cur * 1024 + 512 + b * 64 + lane];
#pragma unroll
        for (int a = 0; a < 4; ++a) {
            h8 af = AB[cur * 1024 + wvu * 256 + a * 64 + lane];
#pragma unroll
            for (int b = 0; b < 8; ++b)
                acc[a][b] = __builtin_amdgcn_mfma_f32_16x16x32_f16(af, bf[b], acc[a][b], 0, 0, 0);
        }
        cur ^= 1;
    }
#undef STAGE

#pragma unroll
    for (int a = 0; a < 4; ++a) {
        const int r0 = rw + a * 16 + lk * 4;
        float s0 = sq[r0 + 0], s1 = sq[r0 + 1], s2 = sq[r0 + 2], s3 = sq[r0 + 3];
        float rm[4] = {INFINITY, INFINITY, INFINITY, INFINITY};
#pragma unroll
        for (int b = 0; b < 8; ++b) {
            float ecv = e2[cw + b * 16 + l15];
            rm[0] = fminf(rm[0], dapprox(s0, acc[a][b][0], ecv));
            rm[1] = fminf(rm[1], dapprox(s1, acc[a][b][1], ecv));
            rm[2] = fminf(rm[2], dapprox(s2, acc[a][b][2], ecv));
            rm[3] = fminf(rm[3], dapprox(s3, acc[a][b][3], ecv));
        }
#pragma unroll
        for (int jj = 0; jj < 4; ++jj) {
            float v = rm[jj];
            v = fminf(v, __shfl_xor(v, 1));
            v = fminf(v, __shfl_xor(v, 2));
            v = fminf(v, __shfl_xor(v, 4));
            v = fminf(v, __shfl_xor(v, 8));
            if (l15 == 0) tmin[(size_t)ct * ROWS + (r0 + jj)] = v;   // [tile][row]
        }
    }
}

// ---------------- kernel 3: per-row threshold + per-tile row lists ----------------
__global__ void k_select(const float* __restrict__ tmin, const float* __restrict__ sabs,
                         float* __restrict__ thr, int* __restrict__ tileCnt,
                         int* __restrict__ tileRows) {
    int row = blockIdx.x * 256 + threadIdx.x;
    if (row >= ROWS) return;
    float g = tmin[row];                              // tile 0
#pragma unroll 8
    for (int i = 1; i < NTILES; ++i) g = fminf(g, tmin[(size_t)i * ROWS + row]);
    float th = g + (sabs[row] * 8e-7f + 6e-4f);       // WIN = 2*err bound (verified)
    thr[row] = th;
    for (int i = 0; i < NTILES; ++i)
        if (tmin[(size_t)i * ROWS + row] <= th) {
            int sl = atomicAdd(&tileCnt[i], 1);
            tileRows[(size_t)i * ROWS + sl] = row;
        }
}

// ---------------- kernel 4: fp16 MFMA pass 2 (qualifying pairs only) -> candidates ----
__global__ __launch_bounds__(256, 2)
void k_mfma_cand(const _Float16* __restrict__ zh, const _Float16* __restrict__ ch,
                 const float* __restrict__ sq, const float* __restrict__ e2,
                 const float* __restrict__ thr, const int* __restrict__ tileCnt,
                 const int* __restrict__ tileRows, int* __restrict__ cnt,
                 int* __restrict__ cands) {
    const int p     = blockIdx.x;                     // 0..511
    const int t     = (p & 7) * 8 + ((p >> 3) & 7);   // tile, XCD-pinned (= pass-1 map)
    const int chunk = p >> 6;                         // 0..7
    const int wave  = threadIdx.x >> 6;
    const int lane  = threadIdx.x & 63;
    const int l15   = lane & 15;
    const int lk    = lane >> 4;
    const int cw    = t * 128;
    const int n     = tileCnt[t];
    const int ngrp  = (n + 63) >> 6;

    for (int g = chunk * 4 + wave; g < ngrp; g += 32) {
        int gi = g * 64 + lane;
        int myrow = (gi < n) ? tileRows[(size_t)t * ROWS + gi] : -1;

        f4v acc[4][8];
#pragma unroll
        for (int a = 0; a < 4; ++a)
#pragma unroll
            for (int b = 0; b < 8; ++b) acc[a][b] = (f4v){0.f, 0.f, 0.f, 0.f};

#pragma unroll 2
        for (int k0 = 0; k0 < D; k0 += 32) {
            h8 bf[8];
#pragma unroll
            for (int b = 0; b < 8; ++b)
                bf[b] = *(const h8*)(ch + (size_t)(cw + b * 16 + l15) * D + k0 + lk * 8);
#pragma unroll
            for (int a = 0; a < 4; ++a) {
                int ra = __shfl(myrow, a * 16 + l15);
                ra = ra < 0 ? 0 : ra;
                h8 af = *(const h8*)(zh + (size_t)ra * D + k0 + lk * 8);
#pragma unroll
                for (int b = 0; b < 8; ++b)
                    acc[a][b] = __builtin_amdgcn_mfma_f32_16x16x32_f16(af, bf[b], acc[a][b], 0, 0, 0);
            }
        }

#pragma unroll
        for (int a = 0; a < 4; ++a) {
#pragma unroll
            for (int jj = 0; jj < 4; ++jj) {
                int rowv = __shfl(myrow, a * 16 + lk * 4 + jj);
                if (rowv < 0) continue;
                float s  = sq[rowv];
                float th = thr[rowv];
#pragma unroll
                for (int b = 0; b < 8; ++b) {
                    int c = cw + b * 16 + l15;
                    float d = dapprox(s, acc[a][b][jj], e2[c]);
                    if (d <= th) {
                        int sl = atomicAdd(&cnt[rowv], 1);
                        if (sl < NSLOT) cands[(size_t)rowv * NSLOT + sl] = c;
                    }
                }
            }
        }
    }
}

// exact distance: verified dual-chain, sequential ascending-k FMA
__device__ __forceinline__ float exact_d(const float* __restrict__ xr,
                                         const float* __restrict__ er,
                                         float s, float ev) {
    float m1 = 0.0f, m2 = 0.0f;
#pragma unroll 8
    for (int k = 0; k < KC; ++k) m1 = __builtin_fmaf(xr[k], er[k], m1);
#pragma unroll 8
    for (int k = KC; k < D; ++k) m2 = __builtin_fmaf(xr[k], er[k], m2);
    float m = __fadd_rn(m1, m2);
    return __fadd_rn(__fsub_rn(s, __fmul_rn(2.0f, m)), ev);
}

// ---------------- kernel 5: exact rescore (wave-per-row, LDS-staged x) ----------------
__global__ __launch_bounds__(256)
void k_rescore(const float* __restrict__ zE, const float* __restrict__ cb,
               const float* __restrict__ sq, const float* __restrict__ e2,
               const int* __restrict__ cnt, const int* __restrict__ cands,
               int* __restrict__ ids, float* __restrict__ outIds) {
    __shared__ float xs[4][D];
    const int wave = threadIdx.x >> 6;
    const int lane = threadIdx.x & 63;
    const int row  = blockIdx.x * 4 + wave;

    const float* xr = zE + (size_t)row * D;
    *(float4*)&xs[wave][lane * 8]     = *(const float4*)(xr + lane * 8);
    *(float4*)&xs[wave][lane * 8 + 4] = *(const float4*)(xr + lane * 8 + 4);
    __syncthreads();

    float s = sq[row];
    int   n = cnt[row];
    float bd = INFINITY;
    int   bi = NCODES - 1;
    if (n <= NSLOT) {
        for (int t = lane; t < n; t += 64) {
            int c = cands[(size_t)row * NSLOT + t];
            float d = exact_d(xs[wave], cb + (size_t)c * D, s, e2[c]);
            if (d < bd || (d == bd && c < bi)) { bd = d; bi = c; }
        }
    } else {                                          // sound fallback (never expected)
        for (int c = lane; c < NCODES; c += 64) {
            float d = exact_d(xs[wave], cb + (size_t)c * D, s, e2[c]);
            if (d < bd || (d == bd && c < bi)) { bd = d; bi = c; }
        }
    }
#pragma unroll
    for (int off = 32; off; off >>= 1) {
        float v2 = __shfl_xor(bd, off);
        int   x2 = __shfl_xor(bi, off);
        if (v2 < bd || (v2 == bd && x2 < bi)) { bd = v2; bi = x2; }
    }
    if (lane == 0) {
        int b = bi < 0 ? 0 : (bi > NCODES - 1 ? NCODES - 1 : bi);
        ids[row] = b;
        outIds[row] = (float)b;
    }
}

// ---------------- kernel 6: gather z_q_st (f32) + loss partials (verified) --------
__global__ void k_gather(const float* __restrict__ zE, const float* __restrict__ cb,
                         const int* __restrict__ ids, float* __restrict__ outZ,
                         double* __restrict__ lossPart) {
    const int tid = threadIdx.x;
    double acc = 0.0;
#pragma unroll
    for (int it = 0; it < 4; ++it) {
        int chunk = blockIdx.x * 256 + tid + it * 1048576;
        int row   = chunk >> 7;
        int koff  = (chunk & 127) << 2;
        int id    = ids[row];
        id = id < 0 ? 0 : (id > NCODES - 1 ? NCODES - 1 : id);
        float4 ze = *(const float4*)(zE + ((size_t)row << 9) + koff);
        float4 zq = *(const float4*)(cb + ((size_t)id << 9) + koff);
        float d0 = __fsub_rn(zq.x, ze.x);
        float d1 = __fsub_rn(zq.y, ze.y);
        float d2 = __fsub_rn(zq.z, ze.z);
        float d3 = __fsub_rn(zq.w, ze.w);
        float4 v;
        v.x = __fadd_rn(ze.x, d0);
        v.y = __fadd_rn(ze.y, d1);
        v.z = __fadd_rn(ze.z, d2);
        v.w = __fadd_rn(ze.w, d3);
        *reinterpret_cast<float4*>(outZ + ((size_t)chunk << 2)) = v;
        acc += (double)d0 * d0 + (double)d1 * d1 + (double)d2 * d2 + (double)d3 * d3;
    }
    for (int off = 32; off; off >>= 1) acc += __shfl_down(acc, off);
    __shared__ double sred[4];
    if ((tid & 63) == 0) sred[tid >> 6] = acc;
    __syncthreads();
    if (tid == 0) lossPart[blockIdx.x] = (sred[0] + sred[1]) + (sred[2] + sred[3]);
}

// ---------------- kernel 7: final loss (verified) ----------------
__global__ void k_loss(const double* __restrict__ lossPart, float* __restrict__ outLoss) {
    const int tid = threadIdx.x;
    double acc = 0.0;
    for (int i = tid; i < 4096; i += 256) acc += lossPart[i];
    for (int off = 32; off; off >>= 1) acc += __shfl_down(acc, off);
    __shared__ double sred[4];
    if ((tid & 63) == 0) sred[tid >> 6] = acc;
    __syncthreads();
    if (tid == 0) {
        double mean = ((sred[0] + sred[1]) + (sred[2] + sred[3])) / 16777216.0;
        float cl = (float)mean;
        *outLoss = __fadd_rn(cl, __fmul_rn(0.25f, cl));
    }
}

extern "C" void kernel_launch(void* const* d_in, const int* in_sizes, int n_in,
                              void* d_out, int out_size, void* d_ws, size_t ws_size,
                              hipStream_t stream) {
    (void)in_sizes; (void)n_in; (void)out_size; (void)ws_size;
    const float* zE = (const float*)d_in[0];
    const float* cb = (const float*)d_in[1];
    float* out = (float*)d_out;
    char*  ws  = (char*)d_ws;
    char*  ob  = (char*)d_out;

    // ws scratch (small)
    float*  sq       = (float*)(ws + 0);              // 128 KiB
    float*  e2       = (float*)(ws + 131072);         // 32 KiB
    int*    ids      = (int*)(ws + 163840);           // 128 KiB
    float*  sabs     = (float*)(ws + 294912);         // 128 KiB
    int*    tileCnt  = (int*)(ws + 425984);           // 256 B
    float*  thr      = (float*)(ws + 430080);         // 128 KiB
    int*    cnt      = (int*)(ws + 561152);           // 128 KiB
    double* lossPart = (double*)(ws + 1343488);       // 32 KiB

    // big scratch inside d_out region 0 (fully overwritten by k_gather afterwards)
    _Float16* zh       = (_Float16*)(ob + 0);            // 32 MiB
    _Float16* ch       = (_Float16*)(ob + 33554432);     //  8 MiB
    float*    tmin     = (float*)(ob + 41943040);        //  8 MiB [tile][row]
    int*      tileRows = (int*)(ob + 50331648);          //  8 MiB
    int*      cands    = (int*)(ob + 58720256);          //  8 MiB (32768 x 64)

    k_prep<<<(ROWS + NCODES) / 4, 256, 0, stream>>>(zE, cb, zh, ch, sq, e2, sabs,
                                                    cnt, tileCnt);
    k_mfma_min<<<16384, 128, 0, stream>>>(zh, ch, sq, e2, tmin);
    k_select<<<ROWS / 256, 256, 0, stream>>>(tmin, sabs, thr, tileCnt, tileRows);
    k_mfma_cand<<<512, 256, 0, stream>>>(zh, ch, sq, e2, thr, tileCnt, tileRows,
                                         cnt, cands);
    k_rescore<<<ROWS / 4, 256, 0, stream>>>(zE, cb, sq, e2, cnt, cands,
                                            ids, out + 16777216);
    k_gather<<<4096, 256, 0, stream>>>(zE, cb, ids, out, lossPart);
    k_loss<<<1, 256, 0, stream>>>(lossPart, out + 16777216 + 32768);
}

// Round 19
// 1078.119 us; speedup vs baseline: 1.0014x; 1.0014x over previous
//
#include <hip/hip_runtime.h>

#define ROWS 32768      // B*T
#define D 512
#define NCODES 8192
#define KC 384          // OpenBLAS sgemm kc panel split (verified exact, rounds 4-18)
#define NTILES 64       // 8192 codes / 128
#define NSLOT 64

typedef _Float16 h8 __attribute__((ext_vector_type(8)));
typedef float f4v __attribute__((ext_vector_type(4)));

// ---------------- kernel 1: fused prep (verified r18) ----------------
__global__ __launch_bounds__(256)
void k_prep(const float* __restrict__ zE, const float* __restrict__ cb,
            _Float16* __restrict__ zh, _Float16* __restrict__ ch,
            float* __restrict__ sq, float* __restrict__ e2,
            float* __restrict__ sabs, int* __restrict__ cnt,
            int* __restrict__ tileCnt) {
    const int wid  = blockIdx.x * 4 + (threadIdx.x >> 6);   // 0..40959
    const int lane = threadIdx.x & 63;
    const bool isrow = wid < ROWS;
    const float* p = isrow ? zE + (size_t)wid * D
                           : cb + (size_t)(wid - ROWS) * D;

    {   // f16 conversion (identical values to rounds 12-18)
        float4 u = *(const float4*)(p + lane * 8);
        float4 v = *(const float4*)(p + lane * 8 + 4);
        if (isrow) {
            h8 o = {(_Float16)u.x, (_Float16)u.y, (_Float16)u.z, (_Float16)u.w,
                    (_Float16)v.x, (_Float16)v.y, (_Float16)v.z, (_Float16)v.w};
            *(h8*)(zh + (size_t)wid * D + lane * 8) = o;
        } else {
            h8 o = {(_Float16)(u.x * 4096.0f), (_Float16)(u.y * 4096.0f),
                    (_Float16)(u.z * 4096.0f), (_Float16)(u.w * 4096.0f),
                    (_Float16)(v.x * 4096.0f), (_Float16)(v.y * 4096.0f),
                    (_Float16)(v.z * 4096.0f), (_Float16)(v.w * 4096.0f)};
            *(h8*)(ch + (size_t)(wid - ROWS) * D + lane * 8) = o;
        }
    }

    float v;
    if (lane < 32) {                                  // np-pairwise-exact sumsq
        const int b = lane >> 3, j = lane & 7;
        const float* q = p + b * 128 + j;
        float r = __fmul_rn(q[0], q[0]);
#pragma unroll
        for (int i = 1; i < 16; ++i) {
            float t = q[i * 8];
            r = __fadd_rn(r, __fmul_rn(t, t));
        }
        v = r;
    } else {
        const int m = lane - 32;
        float sa = 0.0f;
#pragma unroll
        for (int i = 0; i < 16; ++i) sa += fabsf(p[i * 32 + m]);
        v = sa;
    }
    v = __fadd_rn(v, __shfl_xor(v, 1));
    v = __fadd_rn(v, __shfl_xor(v, 2));
    v = __fadd_rn(v, __shfl_xor(v, 4));
    v = __fadd_rn(v, __shfl_xor(v, 8));
    v = __fadd_rn(v, __shfl_xor(v, 16));
    float sa = __shfl(v, 32);
    if (lane == 0) {
        if (isrow) { sq[wid] = v; sabs[wid] = sa; cnt[wid] = 0; }
        else       { e2[wid - ROWS] = v; }
    }
    if (lane == 1 && wid < NTILES) tileCnt[wid] = 0;
}

// approx distance (deterministic; identical in both MFMA kernels)
__device__ __forceinline__ float dapprox(float s, float accv, float ecv) {
    float m = __fmul_rn(accv, 0.000244140625f);       // exact /4096
    return __fadd_rn(__fsub_rn(s, __fmul_rn(2.0f, m)), ecv);
}

// ---------------- kernel 2: fp16 MFMA pass 1 -> per-tile minima ----------------
// 4-wave block = 128 rows x 128 codes; wave owns a 64x64 quadrant -> acc[4][4]
// (64 AGPR) -> 4 waves/SIMD. LDS linear [frag][lane] per global_load_lds contract.
// Per-(row,code) MFMA chain identical to rounds 12-18 -> d~ bit-identical; the
// two code-half row-mins merge via exact fminf -> tmin values identical.
__global__ __launch_bounds__(256, 4)
void k_mfma_min(const _Float16* __restrict__ zh, const _Float16* __restrict__ ch,
                const float* __restrict__ sq, const float* __restrict__ e2,
                float* __restrict__ tmin) {
    __shared__ h8 AB[2 * 1024];   // [buf][A: 8 frags x 64 | B: 8 frags x 64] = 32 KiB

    const int p    = blockIdx.x;                      // 0..16383
    const int ct   = (p & 7) * 8 + ((p >> 3) & 7);    // code tile 0..63 (XCD-local)
    const int rt   = p >> 6;                          // row tile 0..255 (128 rows)
    const int wvu  = __builtin_amdgcn_readfirstlane(threadIdx.x >> 6);  // 0..3
    const int rr   = wvu >> 1;                        // row-group (64 rows)
    const int cc   = wvu & 1;                         // code-half (64 codes)
    const int lane = threadIdx.x & 63;
    const int l15  = lane & 15;
    const int lk   = lane >> 4;
    const int rowBase = rt * 128;
    const int cw   = ct * 128;

    f4v acc[4][4];
#pragma unroll
    for (int a = 0; a < 4; ++a)
#pragma unroll
        for (int b = 0; b < 4; ++b) acc[a][b] = (f4v){0.f, 0.f, 0.f, 0.f};

#define STAGE(buf, k0c)                                                              \
    {                                                                                \
        _Pragma("unroll")                                                            \
        for (int q = 0; q < 2; ++q) {                                                \
            const int fa = wvu * 2 + q;   /* 0..7 = r*4+a */                         \
            const _Float16* srcA = zh + (size_t)(rowBase + (fa >> 2) * 64            \
                                   + (fa & 3) * 16 + l15) * D + (k0c) + lk * 8;      \
            __builtin_amdgcn_global_load_lds(                                        \
                (const __attribute__((address_space(1))) void*)(const void*)srcA,    \
                (__attribute__((address_space(3))) void*)(void*)&AB[(buf) * 1024 + fa * 64], \
                16, 0, 0);                                                           \
            const _Float16* srcB = ch + (size_t)(cw + (fa >> 2) * 64                 \
                                   + (fa & 3) * 16 + l15) * D + (k0c) + lk * 8;      \
            __builtin_amdgcn_global_load_lds(                                        \
                (const __attribute__((address_space(1))) void*)(const void*)srcB,    \
                (__attribute__((address_space(3))) void*)(void*)&AB[(buf) * 1024 + 512 + fa * 64], \
                16, 0, 0);                                                           \
        }                                                                            \
    }

    STAGE(0, 0);
    int cur = 0;
#pragma unroll 1
    for (int ks = 0; ks < 16; ++ks) {                 // k0 = ks*32, ascending
        __syncthreads();                              // staged buf `cur` ready
        if (ks < 15) STAGE(cur ^ 1, (ks + 1) * 32);   // async prefetch next
        h8 bf[4];
#pragma unroll
        for (int b = 0; b < 4; ++b)
            bf[b] = AB[cur * 1024 + 512 + (cc * 4 + b) * 64 + lane];
#pragma unroll
        for (int a = 0; a < 4; ++a) {
            h8 af = AB[cur * 1024 + (rr * 4 + a) * 64 + lane];
#pragma unroll
            for (int b = 0; b < 4; ++b)
                acc[a][b] = __builtin_amdgcn_mfma_f32_16x16x32_f16(af, bf[b], acc[a][b], 0, 0, 0);
        }
        cur ^= 1;
    }
#undef STAGE

    __syncthreads();                                  // done reading AB; reuse as mm
    float* mmf = (float*)AB;                          // [rr][cc][64] row-mins (1 KiB)

#pragma unroll
    for (int a = 0; a < 4; ++a) {
        const int r0 = rowBase + rr * 64 + a * 16 + lk * 4;
        float s0 = sq[r0 + 0], s1 = sq[r0 + 1], s2 = sq[r0 + 2], s3 = sq[r0 + 3];
        float rm[4] = {INFINITY, INFINITY, INFINITY, INFINITY};
#pragma unroll
        for (int b = 0; b < 4; ++b) {
            float ecv = e2[cw + cc * 64 + b * 16 + l15];
            rm[0] = fminf(rm[0], dapprox(s0, acc[a][b][0], ecv));
            rm[1] = fminf(rm[1], dapprox(s1, acc[a][b][1], ecv));
            rm[2] = fminf(rm[2], dapprox(s2, acc[a][b][2], ecv));
            rm[3] = fminf(rm[3], dapprox(s3, acc[a][b][3], ecv));
        }
#pragma unroll
        for (int jj = 0; jj < 4; ++jj) {
            float v = rm[jj];
            v = fminf(v, __shfl_xor(v, 1));
            v = fminf(v, __shfl_xor(v, 2));
            v = fminf(v, __shfl_xor(v, 4));
            v = fminf(v, __shfl_xor(v, 8));
            if (l15 == 0)
                mmf[(rr * 2 + cc) * 64 + a * 16 + lk * 4 + jj] = v;
        }
    }
    __syncthreads();
    if (cc == 0) {                                    // waves 0,2: merge halves
        float v0 = mmf[(rr * 2 + 0) * 64 + lane];
        float v1 = mmf[(rr * 2 + 1) * 64 + lane];
        tmin[(size_t)ct * ROWS + rowBase + rr * 64 + lane] = fminf(v0, v1);
    }
}

// ---------------- kernel 3: per-row threshold + per-tile row lists ----------------
__global__ void k_select(const float* __restrict__ tmin, const float* __restrict__ sabs,
                         float* __restrict__ thr, int* __restrict__ tileCnt,
                         int* __restrict__ tileRows) {
    int row = blockIdx.x * 256 + threadIdx.x;
    if (row >= ROWS) return;
    float g = tmin[row];                              // tile 0
#pragma unroll 8
    for (int i = 1; i < NTILES; ++i) g = fminf(g, tmin[(size_t)i * ROWS + row]);
    float th = g + (sabs[row] * 8e-7f + 6e-4f);       // WIN = 2*err bound (verified)
    thr[row] = th;
    for (int i = 0; i < NTILES; ++i)
        if (tmin[(size_t)i * ROWS + row] <= th) {
            int sl = atomicAdd(&tileCnt[i], 1);
            tileRows[(size_t)i * ROWS + sl] = row;
        }
}

// ---------------- kernel 4: fp16 MFMA pass 2 (qualifying pairs only) -> candidates ----
__global__ __launch_bounds__(256, 2)
void k_mfma_cand(const _Float16* __restrict__ zh, const _Float16* __restrict__ ch,
                 const float* __restrict__ sq, const float* __restrict__ e2,
                 const float* __restrict__ thr, const int* __restrict__ tileCnt,
                 const int* __restrict__ tileRows, int* __restrict__ cnt,
                 int* __restrict__ cands) {
    const int p     = blockIdx.x;                     // 0..511
    const int t     = (p & 7) * 8 + ((p >> 3) & 7);   // tile, XCD-pinned
    const int chunk = p >> 6;                         // 0..7
    const int wave  = threadIdx.x >> 6;
    const int lane  = threadIdx.x & 63;
    const int l15   = lane & 15;
    const int lk    = lane >> 4;
    const int cw    = t * 128;
    const int n     = tileCnt[t];
    const int ngrp  = (n + 63) >> 6;

    for (int g = chunk * 4 + wave; g < ngrp; g += 32) {
        int gi = g * 64 + lane;
        int myrow = (gi < n) ? tileRows[(size_t)t * ROWS + gi] : -1;

        f4v acc[4][8];
#pragma unroll
        for (int a = 0; a < 4; ++a)
#pragma unroll
            for (int b = 0; b < 8; ++b) acc[a][b] = (f4v){0.f, 0.f, 0.f, 0.f};

#pragma unroll 2
        for (int k0 = 0; k0 < D; k0 += 32) {
            h8 bf[8];
#pragma unroll
            for (int b = 0; b < 8; ++b)
                bf[b] = *(const h8*)(ch + (size_t)(cw + b * 16 + l15) * D + k0 + lk * 8);
#pragma unroll
            for (int a = 0; a < 4; ++a) {
                int ra = __shfl(myrow, a * 16 + l15);
                ra = ra < 0 ? 0 : ra;
                h8 af = *(const h8*)(zh + (size_t)ra * D + k0 + lk * 8);
#pragma unroll
                for (int b = 0; b < 8; ++b)
                    acc[a][b] = __builtin_amdgcn_mfma_f32_16x16x32_f16(af, bf[b], acc[a][b], 0, 0, 0);
            }
        }

#pragma unroll
        for (int a = 0; a < 4; ++a) {
#pragma unroll
            for (int jj = 0; jj < 4; ++jj) {
                int rowv = __shfl(myrow, a * 16 + lk * 4 + jj);
                if (rowv < 0) continue;
                float s  = sq[rowv];
                float th = thr[rowv];
#pragma unroll
                for (int b = 0; b < 8; ++b) {
                    int c = cw + b * 16 + l15;
                    float d = dapprox(s, acc[a][b][jj], e2[c]);
                    if (d <= th) {
                        int sl = atomicAdd(&cnt[rowv], 1);
                        if (sl < NSLOT) cands[(size_t)rowv * NSLOT + sl] = c;
                    }
                }
            }
        }
    }
}

// exact distance: verified dual-chain, sequential ascending-k FMA
__device__ __forceinline__ float exact_d(const float* __restrict__ xr,
                                         const float* __restrict__ er,
                                         float s, float ev) {
    float m1 = 0.0f, m2 = 0.0f;
#pragma unroll 8
    for (int k = 0; k < KC; ++k) m1 = __builtin_fmaf(xr[k], er[k], m1);
#pragma unroll 8
    for (int k = KC; k < D; ++k) m2 = __builtin_fmaf(xr[k], er[k], m2);
    float m = __fadd_rn(m1, m2);
    return __fadd_rn(__fsub_rn(s, __fmul_rn(2.0f, m)), ev);
}

// ---------------- kernel 5: exact rescore (wave-per-row, LDS-staged x) ----------------
__global__ __launch_bounds__(256)
void k_rescore(const float* __restrict__ zE, const float* __restrict__ cb,
               const float* __restrict__ sq, const float* __restrict__ e2,
               const int* __restrict__ cnt, const int* __restrict__ cands,
               int* __restrict__ ids, float* __restrict__ outIds) {
    __shared__ float xs[4][D];
    const int wave = threadIdx.x >> 6;
    const int lane = threadIdx.x & 63;
    const int row  = blockIdx.x * 4 + wave;

    const float* xr = zE + (size_t)row * D;
    *(float4*)&xs[wave][lane * 8]     = *(const float4*)(xr + lane * 8);
    *(float4*)&xs[wave][lane * 8 + 4] = *(const float4*)(xr + lane * 8 + 4);
    __syncthreads();

    float s = sq[row];
    int   n = cnt[row];
    float bd = INFINITY;
    int   bi = NCODES - 1;
    if (n <= NSLOT) {
        for (int t = lane; t < n; t += 64) {
            int c = cands[(size_t)row * NSLOT + t];
            float d = exact_d(xs[wave], cb + (size_t)c * D, s, e2[c]);
            if (d < bd || (d == bd && c < bi)) { bd = d; bi = c; }
        }
    } else {                                          // sound fallback (never expected)
        for (int c = lane; c < NCODES; c += 64) {
            float d = exact_d(xs[wave], cb + (size_t)c * D, s, e2[c]);
            if (d < bd || (d == bd && c < bi)) { bd = d; bi = c; }
        }
    }
#pragma unroll
    for (int off = 32; off; off >>= 1) {
        float v2 = __shfl_xor(bd, off);
        int   x2 = __shfl_xor(bi, off);
        if (v2 < bd || (v2 == bd && x2 < bi)) { bd = v2; bi = x2; }
    }
    if (lane == 0) {
        int b = bi < 0 ? 0 : (bi > NCODES - 1 ? NCODES - 1 : bi);
        ids[row] = b;
        outIds[row] = (float)b;
    }
}

// ---------------- kernel 6: gather z_q_st (f32) + loss partials (verified) --------
__global__ void k_gather(const float* __restrict__ zE, const float* __restrict__ cb,
                         const int* __restrict__ ids, float* __restrict__ outZ,
                         double* __restrict__ lossPart) {
    const int tid = threadIdx.x;
    double acc = 0.0;
#pragma unroll
    for (int it = 0; it < 4; ++it) {
        int chunk = blockIdx.x * 256 + tid + it * 1048576;
        int row   = chunk >> 7;
        int koff  = (chunk & 127) << 2;
        int id    = ids[row];
        id = id < 0 ? 0 : (id > NCODES - 1 ? NCODES - 1 : id);
        float4 ze = *(const float4*)(zE + ((size_t)row << 9) + koff);
        float4 zq = *(const float4*)(cb + ((size_t)id << 9) + koff);
        float d0 = __fsub_rn(zq.x, ze.x);
        float d1 = __fsub_rn(zq.y, ze.y);
        float d2 = __fsub_rn(zq.z, ze.z);
        float d3 = __fsub_rn(zq.w, ze.w);
        float4 v;
        v.x = __fadd_rn(ze.x, d0);
        v.y = __fadd_rn(ze.y, d1);
        v.z = __fadd_rn(ze.z, d2);
        v.w = __fadd_rn(ze.w, d3);
        *reinterpret_cast<float4*>(outZ + ((size_t)chunk << 2)) = v;
        acc += (double)d0 * d0 + (double)d1 * d1 + (double)d2 * d2 + (double)d3 * d3;
    }
    for (int off = 32; off; off >>= 1) acc += __shfl_down(acc, off);
    __shared__ double sred[4];
    if ((tid & 63) == 0) sred[tid >> 6] = acc;
    __syncthreads();
    if (tid == 0) lossPart[blockIdx.x] = (sred[0] + sred[1]) + (sred[2] + sred[3]);
}

// ---------------- kernel 7: final loss (verified) ----------------
__global__ void k_loss(const double* __restrict__ lossPart, float* __restrict__ outLoss) {
    const int tid = threadIdx.x;
    double acc = 0.0;
    for (int i = tid; i < 4096; i += 256) acc += lossPart[i];
    for (int off = 32; off; off >>= 1) acc += __shfl_down(acc, off);
    __shared__ double sred[4];
    if ((tid & 63) == 0) sred[tid >> 6] = acc;
    __syncthreads();
    if (tid == 0) {
        double mean = ((sred[0] + sred[1]) + (sred[2] + sred[3])) / 16777216.0;
        float cl = (float)mean;
        *outLoss = __fadd_rn(cl, __fmul_rn(0.25f, cl));
    }
}

extern "C" void kernel_launch(void* const* d_in, const int* in_sizes, int n_in,
                              void* d_out, int out_size, void* d_ws, size_t ws_size,
                              hipStream_t stream) {
    (void)in_sizes; (void)n_in; (void)out_size; (void)ws_size;
    const float* zE = (const float*)d_in[0];
    const float* cb = (const float*)d_in[1];
    float* out = (float*)d_out;
    char*  ws  = (char*)d_ws;
    char*  ob  = (char*)d_out;

    // ws scratch (small)
    float*  sq       = (float*)(ws + 0);              // 128 KiB
    float*  e2       = (float*)(ws + 131072);         // 32 KiB
    int*    ids      = (int*)(ws + 163840);           // 128 KiB
    float*  sabs     = (float*)(ws + 294912);         // 128 KiB
    int*    tileCnt  = (int*)(ws + 425984);           // 256 B
    float*  thr      = (float*)(ws + 430080);         // 128 KiB
    int*    cnt      = (int*)(ws + 561152);           // 128 KiB
    double* lossPart = (double*)(ws + 1343488);       // 32 KiB

    // big scratch inside d_out region 0 (fully overwritten by k_gather afterwards)
    _Float16* zh       = (_Float16*)(ob + 0);            // 32 MiB
    _Float16* ch       = (_Float16*)(ob + 33554432);     //  8 MiB
    float*    tmin     = (float*)(ob + 41943040);        //  8 MiB [tile][row]
    int*      tileRows = (int*)(ob + 50331648);          //  8 MiB
    int*      cands    = (int*)(ob + 58720256);          //  8 MiB (32768 x 64)

    k_prep<<<(ROWS + NCODES) / 4, 256, 0, stream>>>(zE, cb, zh, ch, sq, e2, sabs,
                                                    cnt, tileCnt);
    k_mfma_min<<<16384, 256, 0, stream>>>(zh, ch, sq, e2, tmin);
    k_select<<<ROWS / 256, 256, 0, stream>>>(tmin, sabs, thr, tileCnt, tileRows);
    k_mfma_cand<<<512, 256, 0, stream>>>(zh, ch, sq, e2, thr, tileCnt, tileRows,
                                         cnt, cands);
    k_rescore<<<ROWS / 4, 256, 0, stream>>>(zE, cb, sq, e2, cnt, cands,
                                            ids, out + 16777216);
    k_gather<<<4096, 256, 0, stream>>>(zE, cb, ids, out, lossPart);
    k_loss<<<1, 256, 0, stream>>>(lossPart, out + 16777216 + 32768);
}

// Round 20
// 958.448 us; speedup vs baseline: 1.1264x; 1.1249x over previous
//
#include <hip/hip_runtime.h>

#define ROWS 32768      // B*T
#define D 512
#define NCODES 8192
#define KC 384          // OpenBLAS sgemm kc panel split (verified exact, rounds 4-19)
#define NTILES 64       // 8192 codes / 128
#define NSLOT 64

typedef _Float16 h8 __attribute__((ext_vector_type(8)));
typedef float f4v __attribute__((ext_vector_type(4)));

// ---------------- kernel 1: fused prep (verified r18/r19) ----------------
__global__ __launch_bounds__(256)
void k_prep(const float* __restrict__ zE, const float* __restrict__ cb,
            _Float16* __restrict__ zh, _Float16* __restrict__ ch,
            float* __restrict__ sq, float* __restrict__ e2,
            float* __restrict__ sabs, int* __restrict__ cnt,
            int* __restrict__ tileCnt) {
    const int wid  = blockIdx.x * 4 + (threadIdx.x >> 6);   // 0..40959
    const int lane = threadIdx.x & 63;
    const bool isrow = wid < ROWS;
    const float* p = isrow ? zE + (size_t)wid * D
                           : cb + (size_t)(wid - ROWS) * D;

    {   // f16 conversion (identical values to rounds 12-19)
        float4 u = *(const float4*)(p + lane * 8);
        float4 v = *(const float4*)(p + lane * 8 + 4);
        if (isrow) {
            h8 o = {(_Float16)u.x, (_Float16)u.y, (_Float16)u.z, (_Float16)u.w,
                    (_Float16)v.x, (_Float16)v.y, (_Float16)v.z, (_Float16)v.w};
            *(h8*)(zh + (size_t)wid * D + lane * 8) = o;
        } else {
            h8 o = {(_Float16)(u.x * 4096.0f), (_Float16)(u.y * 4096.0f),
                    (_Float16)(u.z * 4096.0f), (_Float16)(u.w * 4096.0f),
                    (_Float16)(v.x * 4096.0f), (_Float16)(v.y * 4096.0f),
                    (_Float16)(v.z * 4096.0f), (_Float16)(v.w * 4096.0f)};
            *(h8*)(ch + (size_t)(wid - ROWS) * D + lane * 8) = o;
        }
    }

    float v;
    if (lane < 32) {                                  // np-pairwise-exact sumsq
        const int b = lane >> 3, j = lane & 7;
        const float* q = p + b * 128 + j;
        float r = __fmul_rn(q[0], q[0]);
#pragma unroll
        for (int i = 1; i < 16; ++i) {
            float t = q[i * 8];
            r = __fadd_rn(r, __fmul_rn(t, t));
        }
        v = r;
    } else {
        const int m = lane - 32;
        float sa = 0.0f;
#pragma unroll
        for (int i = 0; i < 16; ++i) sa += fabsf(p[i * 32 + m]);
        v = sa;
    }
    v = __fadd_rn(v, __shfl_xor(v, 1));
    v = __fadd_rn(v, __shfl_xor(v, 2));
    v = __fadd_rn(v, __shfl_xor(v, 4));
    v = __fadd_rn(v, __shfl_xor(v, 8));
    v = __fadd_rn(v, __shfl_xor(v, 16));
    float sa = __shfl(v, 32);
    if (lane == 0) {
        if (isrow) { sq[wid] = v; sabs[wid] = sa; cnt[wid] = 0; }
        else       { e2[wid - ROWS] = v; }
    }
    if (lane == 1 && wid < NTILES) tileCnt[wid] = 0;
}

// approx distance (deterministic; identical in both MFMA kernels)
__device__ __forceinline__ float dapprox(float s, float accv, float ecv) {
    float m = __fmul_rn(accv, 0.000244140625f);       // exact /4096
    return __fadd_rn(__fsub_rn(s, __fmul_rn(2.0f, m)), ecv);
}

// ---------------- kernel 2: fp16 MFMA pass 1 -> per-tile minima ----------------
// r17 tile shape (4 waves x [64 rows x 128 codes], acc[4][8]) + T3/T4 pipeline:
// 3 LDS buffers, stage issued AFTER the barrier (buffer being overwritten was
// last read 2 iters ago -> race-free), counted s_waitcnt vmcnt(6) (per-wave
// stage = 6 global_load_lds) so prefetch stays in flight across barriers.
// MFMA accumulate order identical to rounds 12-19 -> d~ bit-identical.
__global__ __launch_bounds__(256, 2)
void k_mfma_min(const _Float16* __restrict__ zh, const _Float16* __restrict__ ch,
                const float* __restrict__ sq, const float* __restrict__ e2,
                float* __restrict__ tmin) {
    __shared__ h8 AB[3 * 1536];   // 3 bufs x [A: 4w x 4a x 64 | B: 8b x 64] = 72 KiB

    const int p    = blockIdx.x;                      // 0..8191
    const int ct   = (p & 7) * 8 + ((p >> 3) & 7);    // code tile 0..63 (XCD-local)
    const int rt   = p >> 6;                          // row tile 0..127
    const int wvu  = __builtin_amdgcn_readfirstlane(threadIdx.x >> 6);  // 0..3
    const int lane = threadIdx.x & 63;
    const int l15  = lane & 15;
    const int lk   = lane >> 4;
    const int rw   = rt * 256 + wvu * 64;
    const int cw   = ct * 128;

    f4v acc[4][8];
#pragma unroll
    for (int a = 0; a < 4; ++a)
#pragma unroll
        for (int b = 0; b < 8; ++b) acc[a][b] = (f4v){0.f, 0.f, 0.f, 0.f};

#define STAGE(buf, k0c)                                                              \
    {                                                                                \
        const int bb0 = (buf) * 1536;                                                \
        _Pragma("unroll")                                                            \
        for (int a = 0; a < 4; ++a) {                                                \
            const _Float16* src = zh + (size_t)(rw + a * 16 + l15) * D + (k0c) + lk * 8; \
            __builtin_amdgcn_global_load_lds(                                        \
                (const __attribute__((address_space(1))) void*)(const void*)src,    \
                (__attribute__((address_space(3))) void*)(void*)&AB[bb0 + wvu * 256 + a * 64], \
                16, 0, 0);                                                           \
        }                                                                            \
        _Pragma("unroll")                                                            \
        for (int j = 0; j < 2; ++j) {                                                \
            const int bb = wvu * 2 + j;                                              \
            const _Float16* src = ch + (size_t)(cw + bb * 16 + l15) * D + (k0c) + lk * 8; \
            __builtin_amdgcn_global_load_lds(                                        \
                (const __attribute__((address_space(1))) void*)(const void*)src,    \
                (__attribute__((address_space(3))) void*)(void*)&AB[bb0 + 1024 + bb * 64], \
                16, 0, 0);                                                           \
        }                                                                            \
    }

    STAGE(0, 0);                                      // prologue: stages 0,1
    STAGE(1, 32);

#pragma unroll 1
    for (int ks = 0; ks < 16; ++ks) {                 // k0 = ks*32, ascending
        const int cur = ks % 3;
        __builtin_amdgcn_sched_barrier(0);
        if (ks < 15) {
            asm volatile("s_waitcnt vmcnt(6)" ::: "memory");   // stage ks done;
        } else {                                               // ks+1 stays in flight
            asm volatile("s_waitcnt vmcnt(0)" ::: "memory");
        }
        __builtin_amdgcn_sched_barrier(0);
        __builtin_amdgcn_s_barrier();                 // all waves' stage ks landed
        __builtin_amdgcn_sched_barrier(0);
        if (ks < 14) STAGE((ks + 2) % 3, (ks + 2) * 32);   // overwrites buf read 2 iters ago

        h8 bf[8];
#pragma unroll
        for (int b = 0; b < 8; ++b) bf[b] = AB[cur * 1536 + 1024 + b * 64 + lane];
#pragma unroll
        for (int a = 0; a < 4; ++a) {
            h8 af = AB[cur * 1536 + wvu * 256 + a * 64 + lane];
#pragma unroll
            for (int b = 0; b < 8; ++b)
                acc[a][b] = __builtin_amdgcn_mfma_f32_16x16x32_f16(af, bf[b], acc[a][b], 0, 0, 0);
        }
    }
#undef STAGE

#pragma unroll
    for (int a = 0; a < 4; ++a) {
        const int r0 = rw + a * 16 + lk * 4;
        float s0 = sq[r0 + 0], s1 = sq[r0 + 1], s2 = sq[r0 + 2], s3 = sq[r0 + 3];
        float rm[4] = {INFINITY, INFINITY, INFINITY, INFINITY};
#pragma unroll
        for (int b = 0; b < 8; ++b) {
            float ecv = e2[cw + b * 16 + l15];
            rm[0] = fminf(rm[0], dapprox(s0, acc[a][b][0], ecv));
            rm[1] = fminf(rm[1], dapprox(s1, acc[a][b][1], ecv));
            rm[2] = fminf(rm[2], dapprox(s2, acc[a][b][2], ecv));
            rm[3] = fminf(rm[3], dapprox(s3, acc[a][b][3], ecv));
        }
#pragma unroll
        for (int jj = 0; jj < 4; ++jj) {
            float v = rm[jj];
            v = fminf(v, __shfl_xor(v, 1));
            v = fminf(v, __shfl_xor(v, 2));
            v = fminf(v, __shfl_xor(v, 4));
            v = fminf(v, __shfl_xor(v, 8));
            if (l15 == 0) tmin[(size_t)ct * ROWS + (r0 + jj)] = v;   // [tile][row]
        }
    }
}

// ---------------- kernel 3: per-row threshold + per-tile row lists ----------------
__global__ void k_select(const float* __restrict__ tmin, const float* __restrict__ sabs,
                         float* __restrict__ thr, int* __restrict__ tileCnt,
                         int* __restrict__ tileRows) {
    int row = blockIdx.x * 256 + threadIdx.x;
    if (row >= ROWS) return;
    float g = tmin[row];                              // tile 0
#pragma unroll 8
    for (int i = 1; i < NTILES; ++i) g = fminf(g, tmin[(size_t)i * ROWS + row]);
    float th = g + (sabs[row] * 8e-7f + 6e-4f);       // WIN = 2*err bound (verified)
    thr[row] = th;
    for (int i = 0; i < NTILES; ++i)
        if (tmin[(size_t)i * ROWS + row] <= th) {
            int sl = atomicAdd(&tileCnt[i], 1);
            tileRows[(size_t)i * ROWS + sl] = row;
        }
}

// ---------------- kernel 4: fp16 MFMA pass 2 (qualifying pairs only) -> candidates ----
__global__ __launch_bounds__(256, 2)
void k_mfma_cand(const _Float16* __restrict__ zh, const _Float16* __restrict__ ch,
                 const float* __restrict__ sq, const float* __restrict__ e2,
                 const float* __restrict__ thr, const int* __restrict__ tileCnt,
                 const int* __restrict__ tileRows, int* __restrict__ cnt,
                 int* __restrict__ cands) {
    const int p     = blockIdx.x;                     // 0..511
    const int t     = (p & 7) * 8 + ((p >> 3) & 7);   // tile, XCD-pinned
    const int chunk = p >> 6;                         // 0..7
    const int wave  = threadIdx.x >> 6;
    const int lane  = threadIdx.x & 63;
    const int l15   = lane & 15;
    const int lk    = lane >> 4;
    const int cw    = t * 128;
    const int n     = tileCnt[t];
    const int ngrp  = (n + 63) >> 6;

    for (int g = chunk * 4 + wave; g < ngrp; g += 32) {
        int gi = g * 64 + lane;
        int myrow = (gi < n) ? tileRows[(size_t)t * ROWS + gi] : -1;

        f4v acc[4][8];
#pragma unroll
        for (int a = 0; a < 4; ++a)
#pragma unroll
            for (int b = 0; b < 8; ++b) acc[a][b] = (f4v){0.f, 0.f, 0.f, 0.f};

#pragma unroll 2
        for (int k0 = 0; k0 < D; k0 += 32) {
            h8 bf[8];
#pragma unroll
            for (int b = 0; b < 8; ++b)
                bf[b] = *(const h8*)(ch + (size_t)(cw + b * 16 + l15) * D + k0 + lk * 8);
#pragma unroll
            for (int a = 0; a < 4; ++a) {
                int ra = __shfl(myrow, a * 16 + l15);
                ra = ra < 0 ? 0 : ra;
                h8 af = *(const h8*)(zh + (size_t)ra * D + k0 + lk * 8);
#pragma unroll
                for (int b = 0; b < 8; ++b)
                    acc[a][b] = __builtin_amdgcn_mfma_f32_16x16x32_f16(af, bf[b], acc[a][b], 0, 0, 0);
            }
        }

#pragma unroll
        for (int a = 0; a < 4; ++a) {
#pragma unroll
            for (int jj = 0; jj < 4; ++jj) {
                int rowv = __shfl(myrow, a * 16 + lk * 4 + jj);
                if (rowv < 0) continue;
                float s  = sq[rowv];
                float th = thr[rowv];
#pragma unroll
                for (int b = 0; b < 8; ++b) {
                    int c = cw + b * 16 + l15;
                    float d = dapprox(s, acc[a][b][jj], e2[c]);
                    if (d <= th) {
                        int sl = atomicAdd(&cnt[rowv], 1);
                        if (sl < NSLOT) cands[(size_t)rowv * NSLOT + sl] = c;
                    }
                }
            }
        }
    }
}

// exact distance: verified dual-chain, sequential ascending-k FMA
__device__ __forceinline__ float exact_d(const float* __restrict__ xr,
                                         const float* __restrict__ er,
                                         float s, float ev) {
    float m1 = 0.0f, m2 = 0.0f;
#pragma unroll 8
    for (int k = 0; k < KC; ++k) m1 = __builtin_fmaf(xr[k], er[k], m1);
#pragma unroll 8
    for (int k = KC; k < D; ++k) m2 = __builtin_fmaf(xr[k], er[k], m2);
    float m = __fadd_rn(m1, m2);
    return __fadd_rn(__fsub_rn(s, __fmul_rn(2.0f, m)), ev);
}

// ---------------- kernel 5: exact rescore (wave-per-row, LDS-staged x) ----------------
__global__ __launch_bounds__(256)
void k_rescore(const float* __restrict__ zE, const float* __restrict__ cb,
               const float* __restrict__ sq, const float* __restrict__ e2,
               const int* __restrict__ cnt, const int* __restrict__ cands,
               int* __restrict__ ids, float* __restrict__ outIds) {
    __shared__ float xs[4][D];
    const int wave = threadIdx.x >> 6;
    const int lane = threadIdx.x & 63;
    const int row  = blockIdx.x * 4 + wave;

    const float* xr = zE + (size_t)row * D;
    *(float4*)&xs[wave][lane * 8]     = *(const float4*)(xr + lane * 8);
    *(float4*)&xs[wave][lane * 8 + 4] = *(const float4*)(xr + lane * 8 + 4);
    __syncthreads();

    float s = sq[row];
    int   n = cnt[row];
    float bd = INFINITY;
    int   bi = NCODES - 1;
    if (n <= NSLOT) {
        for (int t = lane; t < n; t += 64) {
            int c = cands[(size_t)row * NSLOT + t];
            float d = exact_d(xs[wave], cb + (size_t)c * D, s, e2[c]);
            if (d < bd || (d == bd && c < bi)) { bd = d; bi = c; }
        }
    } else {                                          // sound fallback (never expected)
        for (int c = lane; c < NCODES; c += 64) {
            float d = exact_d(xs[wave], cb + (size_t)c * D, s, e2[c]);
            if (d < bd || (d == bd && c < bi)) { bd = d; bi = c; }
        }
    }
#pragma unroll
    for (int off = 32; off; off >>= 1) {
        float v2 = __shfl_xor(bd, off);
        int   x2 = __shfl_xor(bi, off);
        if (v2 < bd || (v2 == bd && x2 < bi)) { bd = v2; bi = x2; }
    }
    if (lane == 0) {
        int b = bi < 0 ? 0 : (bi > NCODES - 1 ? NCODES - 1 : bi);
        ids[row] = b;
        outIds[row] = (float)b;
    }
}

// ---------------- kernel 6: gather z_q_st (f32) + loss partials (verified) --------
__global__ void k_gather(const float* __restrict__ zE, const float* __restrict__ cb,
                         const int* __restrict__ ids, float* __restrict__ outZ,
                         double* __restrict__ lossPart) {
    const int tid = threadIdx.x;
    double acc = 0.0;
#pragma unroll
    for (int it = 0; it < 4; ++it) {
        int chunk = blockIdx.x * 256 + tid + it * 1048576;
        int row   = chunk >> 7;
        int koff  = (chunk & 127) << 2;
        int id    = ids[row];
        id = id < 0 ? 0 : (id > NCODES - 1 ? NCODES - 1 : id);
        float4 ze = *(const float4*)(zE + ((size_t)row << 9) + koff);
        float4 zq = *(const float4*)(cb + ((size_t)id << 9) + koff);
        float d0 = __fsub_rn(zq.x, ze.x);
        float d1 = __fsub_rn(zq.y, ze.y);
        float d2 = __fsub_rn(zq.z, ze.z);
        float d3 = __fsub_rn(zq.w, ze.w);
        float4 v;
        v.x = __fadd_rn(ze.x, d0);
        v.y = __fadd_rn(ze.y, d1);
        v.z = __fadd_rn(ze.z, d2);
        v.w = __fadd_rn(ze.w, d3);
        *reinterpret_cast<float4*>(outZ + ((size_t)chunk << 2)) = v;
        acc += (double)d0 * d0 + (double)d1 * d1 + (double)d2 * d2 + (double)d3 * d3;
    }
    for (int off = 32; off; off >>= 1) acc += __shfl_down(acc, off);
    __shared__ double sred[4];
    if ((tid & 63) == 0) sred[tid >> 6] = acc;
    __syncthreads();
    if (tid == 0) lossPart[blockIdx.x] = (sred[0] + sred[1]) + (sred[2] + sred[3]);
}

// ---------------- kernel 7: final loss (verified) ----------------
__global__ void k_loss(const double* __restrict__ lossPart, float* __restrict__ outLoss) {
    const int tid = threadIdx.x;
    double acc = 0.0;
    for (int i = tid; i < 4096; i += 256) acc += lossPart[i];
    for (int off = 32; off; off >>= 1) acc += __shfl_down(acc, off);
    __shared__ double sred[4];
    if ((tid & 63) == 0) sred[tid >> 6] = acc;
    __syncthreads();
    if (tid == 0) {
        double mean = ((sred[0] + sred[1]) + (sred[2] + sred[3])) / 16777216.0;
        float cl = (float)mean;
        *outLoss = __fadd_rn(cl, __fmul_rn(0.25f, cl));
    }
}

extern "C" void kernel_launch(void* const* d_in, const int* in_sizes, int n_in,
                              void* d_out, int out_size, void* d_ws, size_t ws_size,
                              hipStream_t stream) {
    (void)in_sizes; (void)n_in; (void)out_size; (void)ws_size;
    const float* zE = (const float*)d_in[0];
    const float* cb = (const float*)d_in[1];
    float* out = (float*)d_out;
    char*  ws  = (char*)d_ws;
    char*  ob  = (char*)d_out;

    // ws scratch (small)
    float*  sq       = (float*)(ws + 0);              // 128 KiB
    float*  e2       = (float*)(ws + 131072);         // 32 KiB
    int*    ids      = (int*)(ws + 163840);           // 128 KiB
    float*  sabs     = (float*)(ws + 294912);         // 128 KiB
    int*    tileCnt  = (int*)(ws + 425984);           // 256 B
    float*  thr      = (float*)(ws + 430080);         // 128 KiB
    int*    cnt      = (int*)(ws + 561152);           // 128 KiB
    double* lossPart = (double*)(ws + 1343488);       // 32 KiB

    // big scratch inside d_out region 0 (fully overwritten by k_gather afterwards)
    _Float16* zh       = (_Float16*)(ob + 0);            // 32 MiB
    _Float16* ch       = (_Float16*)(ob + 33554432);     //  8 MiB
    float*    tmin     = (float*)(ob + 41943040);        //  8 MiB [tile][row]
    int*      tileRows = (int*)(ob + 50331648);          //  8 MiB
    int*      cands    = (int*)(ob + 58720256);          //  8 MiB (32768 x 64)

    k_prep<<<(ROWS + NCODES) / 4, 256, 0, stream>>>(zE, cb, zh, ch, sq, e2, sabs,
                                                    cnt, tileCnt);
    k_mfma_min<<<8192, 256, 0, stream>>>(zh, ch, sq, e2, tmin);
    k_select<<<ROWS / 256, 256, 0, stream>>>(tmin, sabs, thr, tileCnt, tileRows);
    k_mfma_cand<<<512, 256, 0, stream>>>(zh, ch, sq, e2, thr, tileCnt, tileRows,
                                         cnt, cands);
    k_rescore<<<ROWS / 4, 256, 0, stream>>>(zE, cb, sq, e2, cnt, cands,
                                            ids, out + 16777216);
    k_gather<<<4096, 256, 0, stream>>>(zE, cb, ids, out, lossPart);
    k_loss<<<1, 256, 0, stream>>>(lossPart, out + 16777216 + 32768);
}

// Round 21
// 691.638 us; speedup vs baseline: 1.5610x; 1.3858x over previous
//
#include <hip/hip_runtime.h>

#define ROWS 32768      // B*T
#define D 512
#define NCODES 8192
#define KC 384          // OpenBLAS sgemm kc panel split (verified exact, rounds 4-20)
#define NTILES 64       // 8192 codes / 128
#define NSLOT 64

typedef _Float16 h8 __attribute__((ext_vector_type(8)));
typedef float f4v __attribute__((ext_vector_type(4)));

// ---------------- kernel 1: fused prep (verified r18-r20) ----------------
__global__ __launch_bounds__(256)
void k_prep(const float* __restrict__ zE, const float* __restrict__ cb,
            _Float16* __restrict__ zh, _Float16* __restrict__ ch,
            float* __restrict__ sq, float* __restrict__ e2,
            float* __restrict__ sabs, int* __restrict__ cnt,
            int* __restrict__ tileCnt) {
    const int wid  = blockIdx.x * 4 + (threadIdx.x >> 6);   // 0..40959
    const int lane = threadIdx.x & 63;
    const bool isrow = wid < ROWS;
    const float* p = isrow ? zE + (size_t)wid * D
                           : cb + (size_t)(wid - ROWS) * D;

    {   // f16 conversion (identical values to rounds 12-20)
        float4 u = *(const float4*)(p + lane * 8);
        float4 v = *(const float4*)(p + lane * 8 + 4);
        if (isrow) {
            h8 o = {(_Float16)u.x, (_Float16)u.y, (_Float16)u.z, (_Float16)u.w,
                    (_Float16)v.x, (_Float16)v.y, (_Float16)v.z, (_Float16)v.w};
            *(h8*)(zh + (size_t)wid * D + lane * 8) = o;
        } else {
            h8 o = {(_Float16)(u.x * 4096.0f), (_Float16)(u.y * 4096.0f),
                    (_Float16)(u.z * 4096.0f), (_Float16)(u.w * 4096.0f),
                    (_Float16)(v.x * 4096.0f), (_Float16)(v.y * 4096.0f),
                    (_Float16)(v.z * 4096.0f), (_Float16)(v.w * 4096.0f)};
            *(h8*)(ch + (size_t)(wid - ROWS) * D + lane * 8) = o;
        }
    }

    float v;
    if (lane < 32) {                                  // np-pairwise-exact sumsq
        const int b = lane >> 3, j = lane & 7;
        const float* q = p + b * 128 + j;
        float r = __fmul_rn(q[0], q[0]);
#pragma unroll
        for (int i = 1; i < 16; ++i) {
            float t = q[i * 8];
            r = __fadd_rn(r, __fmul_rn(t, t));
        }
        v = r;
    } else {
        const int m = lane - 32;
        float sa = 0.0f;
#pragma unroll
        for (int i = 0; i < 16; ++i) sa += fabsf(p[i * 32 + m]);
        v = sa;
    }
    v = __fadd_rn(v, __shfl_xor(v, 1));
    v = __fadd_rn(v, __shfl_xor(v, 2));
    v = __fadd_rn(v, __shfl_xor(v, 4));
    v = __fadd_rn(v, __shfl_xor(v, 8));
    v = __fadd_rn(v, __shfl_xor(v, 16));
    float sa = __shfl(v, 32);
    if (lane == 0) {
        if (isrow) { sq[wid] = v; sabs[wid] = sa; cnt[wid] = 0; }
        else       { e2[wid - ROWS] = v; }
    }
    if (lane == 1 && wid < NTILES) tileCnt[wid] = 0;
}

// approx distance (deterministic; identical in both MFMA kernels)
__device__ __forceinline__ float dapprox(float s, float accv, float ecv) {
    float m = __fmul_rn(accv, 0.000244140625f);       // exact /4096
    return __fadd_rn(__fsub_rn(s, __fmul_rn(2.0f, m)), ecv);
}

// ---------------- kernel 2: fp16 MFMA pass 1 -> per-tile minima (verified r20) ----
__global__ __launch_bounds__(256, 2)
void k_mfma_min(const _Float16* __restrict__ zh, const _Float16* __restrict__ ch,
                const float* __restrict__ sq, const float* __restrict__ e2,
                float* __restrict__ tmin) {
    __shared__ h8 AB[3 * 1536];   // 3 bufs x [A: 4w x 4a x 64 | B: 8b x 64] = 72 KiB

    const int p    = blockIdx.x;                      // 0..8191
    const int ct   = (p & 7) * 8 + ((p >> 3) & 7);    // code tile 0..63 (XCD-local)
    const int rt   = p >> 6;                          // row tile 0..127
    const int wvu  = __builtin_amdgcn_readfirstlane(threadIdx.x >> 6);  // 0..3
    const int lane = threadIdx.x & 63;
    const int l15  = lane & 15;
    const int lk   = lane >> 4;
    const int rw   = rt * 256 + wvu * 64;
    const int cw   = ct * 128;

    f4v acc[4][8];
#pragma unroll
    for (int a = 0; a < 4; ++a)
#pragma unroll
        for (int b = 0; b < 8; ++b) acc[a][b] = (f4v){0.f, 0.f, 0.f, 0.f};

#define STAGE(buf, k0c)                                                              \
    {                                                                                \
        const int bb0 = (buf) * 1536;                                                \
        _Pragma("unroll")                                                            \
        for (int a = 0; a < 4; ++a) {                                                \
            const _Float16* src = zh + (size_t)(rw + a * 16 + l15) * D + (k0c) + lk * 8; \
            __builtin_amdgcn_global_load_lds(                                        \
                (const __attribute__((address_space(1))) void*)(const void*)src,    \
                (__attribute__((address_space(3))) void*)(void*)&AB[bb0 + wvu * 256 + a * 64], \
                16, 0, 0);                                                           \
        }                                                                            \
        _Pragma("unroll")                                                            \
        for (int j = 0; j < 2; ++j) {                                                \
            const int bb = wvu * 2 + j;                                              \
            const _Float16* src = ch + (size_t)(cw + bb * 16 + l15) * D + (k0c) + lk * 8; \
            __builtin_amdgcn_global_load_lds(                                        \
                (const __attribute__((address_space(1))) void*)(const void*)src,    \
                (__attribute__((address_space(3))) void*)(void*)&AB[bb0 + 1024 + bb * 64], \
                16, 0, 0);                                                           \
        }                                                                            \
    }

    STAGE(0, 0);                                      // prologue: stages 0,1
    STAGE(1, 32);

#pragma unroll 1
    for (int ks = 0; ks < 16; ++ks) {                 // k0 = ks*32, ascending
        const int cur = ks % 3;
        __builtin_amdgcn_sched_barrier(0);
        if (ks < 15) {
            asm volatile("s_waitcnt vmcnt(6)" ::: "memory");   // stage ks done;
        } else {                                               // ks+1 stays in flight
            asm volatile("s_waitcnt vmcnt(0)" ::: "memory");
        }
        __builtin_amdgcn_sched_barrier(0);
        __builtin_amdgcn_s_barrier();                 // all waves' stage ks landed
        __builtin_amdgcn_sched_barrier(0);
        if (ks < 14) STAGE((ks + 2) % 3, (ks + 2) * 32);

        h8 bf[8];
#pragma unroll
        for (int b = 0; b < 8; ++b) bf[b] = AB[cur * 1536 + 1024 + b * 64 + lane];
#pragma unroll
        for (int a = 0; a < 4; ++a) {
            h8 af = AB[cur * 1536 + wvu * 256 + a * 64 + lane];
#pragma unroll
            for (int b = 0; b < 8; ++b)
                acc[a][b] = __builtin_amdgcn_mfma_f32_16x16x32_f16(af, bf[b], acc[a][b], 0, 0, 0);
        }
    }
#undef STAGE

#pragma unroll
    for (int a = 0; a < 4; ++a) {
        const int r0 = rw + a * 16 + lk * 4;
        float s0 = sq[r0 + 0], s1 = sq[r0 + 1], s2 = sq[r0 + 2], s3 = sq[r0 + 3];
        float rm[4] = {INFINITY, INFINITY, INFINITY, INFINITY};
#pragma unroll
        for (int b = 0; b < 8; ++b) {
            float ecv = e2[cw + b * 16 + l15];
            rm[0] = fminf(rm[0], dapprox(s0, acc[a][b][0], ecv));
            rm[1] = fminf(rm[1], dapprox(s1, acc[a][b][1], ecv));
            rm[2] = fminf(rm[2], dapprox(s2, acc[a][b][2], ecv));
            rm[3] = fminf(rm[3], dapprox(s3, acc[a][b][3], ecv));
        }
#pragma unroll
        for (int jj = 0; jj < 4; ++jj) {
            float v = rm[jj];
            v = fminf(v, __shfl_xor(v, 1));
            v = fminf(v, __shfl_xor(v, 2));
            v = fminf(v, __shfl_xor(v, 4));
            v = fminf(v, __shfl_xor(v, 8));
            if (l15 == 0) tmin[(size_t)ct * ROWS + (r0 + jj)] = v;   // [tile][row]
        }
    }
}

// ---------------- kernel 3: select — block-aggregated (kills atomic contention) ----
// Phase 1: qualify rows into LDS per-tile lists (LDS atomics). Phase 2: one
// global atomicAdd per (block,tile) reserves a contiguous range. Phase 3: bulk
// write. tileRows ORDER differs from r20 but the SET is identical; downstream
// (exact rescore, lexicographic min) is order-independent -> outputs unchanged.
__global__ __launch_bounds__(256)
void k_select(const float* __restrict__ tmin, const float* __restrict__ sabs,
              float* __restrict__ thr, int* __restrict__ tileCnt,
              int* __restrict__ tileRows) {
    __shared__ int           lcnt[NTILES];
    __shared__ int           lbase[NTILES];
    __shared__ unsigned char lrow[NTILES][256];       // row offsets within block

    const int tid     = threadIdx.x;
    const int rowBase = blockIdx.x * 256;
    const int row     = rowBase + tid;

    if (tid < NTILES) lcnt[tid] = 0;
    __syncthreads();

    float g = tmin[row];                              // tile 0
#pragma unroll 8
    for (int i = 1; i < NTILES; ++i) g = fminf(g, tmin[(size_t)i * ROWS + row]);
    float th = g + (sabs[row] * 8e-7f + 6e-4f);       // WIN = 2*err bound (verified)
    thr[row] = th;
    for (int i = 0; i < NTILES; ++i)
        if (tmin[(size_t)i * ROWS + row] <= th) {
            int pos = atomicAdd(&lcnt[i], 1);         // LDS atomic: cheap
            lrow[i][pos] = (unsigned char)tid;
        }
    __syncthreads();

    if (tid < NTILES && lcnt[tid] > 0)
        lbase[tid] = atomicAdd(&tileCnt[tid], lcnt[tid]);   // 1 global atomic/(blk,tile)
    __syncthreads();

    for (int i = 0; i < NTILES; ++i) {
        int n = lcnt[i];
        for (int j = tid; j < n; j += 256)
            tileRows[(size_t)i * ROWS + lbase[i] + j] = rowBase + lrow[i][j];
    }
}

// ---------------- kernel 4: fp16 MFMA pass 2 (qualifying pairs only) -> candidates ----
__global__ __launch_bounds__(256, 2)
void k_mfma_cand(const _Float16* __restrict__ zh, const _Float16* __restrict__ ch,
                 const float* __restrict__ sq, const float* __restrict__ e2,
                 const float* __restrict__ thr, const int* __restrict__ tileCnt,
                 const int* __restrict__ tileRows, int* __restrict__ cnt,
                 int* __restrict__ cands) {
    const int p     = blockIdx.x;                     // 0..511
    const int t     = (p & 7) * 8 + ((p >> 3) & 7);   // tile, XCD-pinned
    const int chunk = p >> 6;                         // 0..7
    const int wave  = threadIdx.x >> 6;
    const int lane  = threadIdx.x & 63;
    const int l15   = lane & 15;
    const int lk    = lane >> 4;
    const int cw    = t * 128;
    const int n     = tileCnt[t];
    const int ngrp  = (n + 63) >> 6;

    for (int g = chunk * 4 + wave; g < ngrp; g += 32) {
        int gi = g * 64 + lane;
        int myrow = (gi < n) ? tileRows[(size_t)t * ROWS + gi] : -1;

        f4v acc[4][8];
#pragma unroll
        for (int a = 0; a < 4; ++a)
#pragma unroll
            for (int b = 0; b < 8; ++b) acc[a][b] = (f4v){0.f, 0.f, 0.f, 0.f};

#pragma unroll 2
        for (int k0 = 0; k0 < D; k0 += 32) {
            h8 bf[8];
#pragma unroll
            for (int b = 0; b < 8; ++b)
                bf[b] = *(const h8*)(ch + (size_t)(cw + b * 16 + l15) * D + k0 + lk * 8);
#pragma unroll
            for (int a = 0; a < 4; ++a) {
                int ra = __shfl(myrow, a * 16 + l15);
                ra = ra < 0 ? 0 : ra;
                h8 af = *(const h8*)(zh + (size_t)ra * D + k0 + lk * 8);
#pragma unroll
                for (int b = 0; b < 8; ++b)
                    acc[a][b] = __builtin_amdgcn_mfma_f32_16x16x32_f16(af, bf[b], acc[a][b], 0, 0, 0);
            }
        }

#pragma unroll
        for (int a = 0; a < 4; ++a) {
#pragma unroll
            for (int jj = 0; jj < 4; ++jj) {
                int rowv = __shfl(myrow, a * 16 + lk * 4 + jj);
                if (rowv < 0) continue;
                float s  = sq[rowv];
                float th = thr[rowv];
#pragma unroll
                for (int b = 0; b < 8; ++b) {
                    int c = cw + b * 16 + l15;
                    float d = dapprox(s, acc[a][b][jj], e2[c]);
                    if (d <= th) {
                        int sl = atomicAdd(&cnt[rowv], 1);
                        if (sl < NSLOT) cands[(size_t)rowv * NSLOT + sl] = c;
                    }
                }
            }
        }
    }
}

// exact distance: verified dual-chain, sequential ascending-k FMA
__device__ __forceinline__ float exact_d(const float* __restrict__ xr,
                                         const float* __restrict__ er,
                                         float s, float ev) {
    float m1 = 0.0f, m2 = 0.0f;
#pragma unroll 8
    for (int k = 0; k < KC; ++k) m1 = __builtin_fmaf(xr[k], er[k], m1);
#pragma unroll 8
    for (int k = KC; k < D; ++k) m2 = __builtin_fmaf(xr[k], er[k], m2);
    float m = __fadd_rn(m1, m2);
    return __fadd_rn(__fsub_rn(s, __fmul_rn(2.0f, m)), ev);
}

// ---------------- kernel 5: exact rescore (wave-per-row, LDS-staged x) ----------------
__global__ __launch_bounds__(256)
void k_rescore(const float* __restrict__ zE, const float* __restrict__ cb,
               const float* __restrict__ sq, const float* __restrict__ e2,
               const int* __restrict__ cnt, const int* __restrict__ cands,
               int* __restrict__ ids, float* __restrict__ outIds) {
    __shared__ float xs[4][D];
    const int wave = threadIdx.x >> 6;
    const int lane = threadIdx.x & 63;
    const int row  = blockIdx.x * 4 + wave;

    const float* xr = zE + (size_t)row * D;
    *(float4*)&xs[wave][lane * 8]     = *(const float4*)(xr + lane * 8);
    *(float4*)&xs[wave][lane * 8 + 4] = *(const float4*)(xr + lane * 8 + 4);
    __syncthreads();

    float s = sq[row];
    int   n = cnt[row];
    float bd = INFINITY;
    int   bi = NCODES - 1;
    if (n <= NSLOT) {
        for (int t = lane; t < n; t += 64) {
            int c = cands[(size_t)row * NSLOT + t];
            float d = exact_d(xs[wave], cb + (size_t)c * D, s, e2[c]);
            if (d < bd || (d == bd && c < bi)) { bd = d; bi = c; }
        }
    } else {                                          // sound fallback (never expected)
        for (int c = lane; c < NCODES; c += 64) {
            float d = exact_d(xs[wave], cb + (size_t)c * D, s, e2[c]);
            if (d < bd || (d == bd && c < bi)) { bd = d; bi = c; }
        }
    }
#pragma unroll
    for (int off = 32; off; off >>= 1) {
        float v2 = __shfl_xor(bd, off);
        int   x2 = __shfl_xor(bi, off);
        if (v2 < bd || (v2 == bd && x2 < bi)) { bd = v2; bi = x2; }
    }
    if (lane == 0) {
        int b = bi < 0 ? 0 : (bi > NCODES - 1 ? NCODES - 1 : bi);
        ids[row] = b;
        outIds[row] = (float)b;
    }
}

// ---------------- kernel 6: gather z_q_st (f32) + loss partials (verified) --------
__global__ void k_gather(const float* __restrict__ zE, const float* __restrict__ cb,
                         const int* __restrict__ ids, float* __restrict__ outZ,
                         double* __restrict__ lossPart) {
    const int tid = threadIdx.x;
    double acc = 0.0;
#pragma unroll
    for (int it = 0; it < 4; ++it) {
        int chunk = blockIdx.x * 256 + tid + it * 1048576;
        int row   = chunk >> 7;
        int koff  = (chunk & 127) << 2;
        int id    = ids[row];
        id = id < 0 ? 0 : (id > NCODES - 1 ? NCODES - 1 : id);
        float4 ze = *(const float4*)(zE + ((size_t)row << 9) + koff);
        float4 zq = *(const float4*)(cb + ((size_t)id << 9) + koff);
        float d0 = __fsub_rn(zq.x, ze.x);
        float d1 = __fsub_rn(zq.y, ze.y);
        float d2 = __fsub_rn(zq.z, ze.z);
        float d3 = __fsub_rn(zq.w, ze.w);
        float4 v;
        v.x = __fadd_rn(ze.x, d0);
        v.y = __fadd_rn(ze.y, d1);
        v.z = __fadd_rn(ze.z, d2);
        v.w = __fadd_rn(ze.w, d3);
        *reinterpret_cast<float4*>(outZ + ((size_t)chunk << 2)) = v;
        acc += (double)d0 * d0 + (double)d1 * d1 + (double)d2 * d2 + (double)d3 * d3;
    }
    for (int off = 32; off; off >>= 1) acc += __shfl_down(acc, off);
    __shared__ double sred[4];
    if ((tid & 63) == 0) sred[tid >> 6] = acc;
    __syncthreads();
    if (tid == 0) lossPart[blockIdx.x] = (sred[0] + sred[1]) + (sred[2] + sred[3]);
}

// ---------------- kernel 7: final loss (verified) ----------------
__global__ void k_loss(const double* __restrict__ lossPart, float* __restrict__ outLoss) {
    const int tid = threadIdx.x;
    double acc = 0.0;
    for (int i = tid; i < 4096; i += 256) acc += lossPart[i];
    for (int off = 32; off; off >>= 1) acc += __shfl_down(acc, off);
    __shared__ double sred[4];
    if ((tid & 63) == 0) sred[tid >> 6] = acc;
    __syncthreads();
    if (tid == 0) {
        double mean = ((sred[0] + sred[1]) + (sred[2] + sred[3])) / 16777216.0;
        float cl = (float)mean;
        *outLoss = __fadd_rn(cl, __fmul_rn(0.25f, cl));
    }
}

extern "C" void kernel_launch(void* const* d_in, const int* in_sizes, int n_in,
                              void* d_out, int out_size, void* d_ws, size_t ws_size,
                              hipStream_t stream) {
    (void)in_sizes; (void)n_in; (void)out_size; (void)ws_size;
    const float* zE = (const float*)d_in[0];
    const float* cb = (const float*)d_in[1];
    float* out = (float*)d_out;
    char*  ws  = (char*)d_ws;
    char*  ob  = (char*)d_out;

    // ws scratch (small)
    float*  sq       = (float*)(ws + 0);              // 128 KiB
    float*  e2       = (float*)(ws + 131072);         // 32 KiB
    int*    ids      = (int*)(ws + 163840);           // 128 KiB
    float*  sabs     = (float*)(ws + 294912);         // 128 KiB
    int*    tileCnt  = (int*)(ws + 425984);           // 256 B
    float*  thr      = (float*)(ws + 430080);         // 128 KiB
    int*    cnt      = (int*)(ws + 561152);           // 128 KiB
    double* lossPart = (double*)(ws + 1343488);       // 32 KiB

    // big scratch inside d_out region 0 (fully overwritten by k_gather afterwards)
    _Float16* zh       = (_Float16*)(ob + 0);            // 32 MiB
    _Float16* ch       = (_Float16*)(ob + 33554432);     //  8 MiB
    float*    tmin     = (float*)(ob + 41943040);        //  8 MiB [tile][row]
    int*      tileRows = (int*)(ob + 50331648);          //  8 MiB
    int*      cands    = (int*)(ob + 58720256);          //  8 MiB (32768 x 64)

    k_prep<<<(ROWS + NCODES) / 4, 256, 0, stream>>>(zE, cb, zh, ch, sq, e2, sabs,
                                                    cnt, tileCnt);
    k_mfma_min<<<8192, 256, 0, stream>>>(zh, ch, sq, e2, tmin);
    k_select<<<ROWS / 256, 256, 0, stream>>>(tmin, sabs, thr, tileCnt, tileRows);
    k_mfma_cand<<<512, 256, 0, stream>>>(zh, ch, sq, e2, thr, tileCnt, tileRows,
                                         cnt, cands);
    k_rescore<<<ROWS / 4, 256, 0, stream>>>(zE, cb, sq, e2, cnt, cands,
                                            ids, out + 16777216);
    k_gather<<<4096, 256, 0, stream>>>(zE, cb, ids, out, lossPart);
    k_loss<<<1, 256, 0, stream>>>(lossPart, out + 16777216 + 32768);
}